// Round 4
// baseline (1011.518 us; speedup 1.0000x reference)
//
#include <hip/hip_runtime.h>

// DIAGNOSTIC ROUND. Output correctness is preserved: the final fused kernel
// rewrites every out cell; earlier probe kernels may write garbage.
// B=8, C=128, H=W=256 -> x slices 65536 f32, out slices 67600 f32 (260x260).

typedef float f32x4 __attribute__((ext_vector_type(4)));
typedef float f32x2 __attribute__((ext_vector_type(2)));

__device__ __forceinline__ int bmap(int r) { return r < 4 ? r : r - 251; }

// ---------------- probes ----------------

// Pure linear float4 write over the whole out buffer (fill-kernel analog).
__global__ __launch_bounds__(512) void probe_wlin(float* out, int reps)
{
    const int tid = threadIdx.x;
    for (int rep = 0; rep < reps; ++rep) {
        int bc = (blockIdx.x + rep * 331) & 1023;
        f32x4* os = (f32x4*)(out + (size_t)bc * 67600);   // 270400 B, 16B-aligned
        f32x4 val = {(float)rep, 0.f, 0.f, 0.f};
        for (int idx = tid; idx < 16900; idx += 512) os[idx] = val;
        asm volatile("" ::: "memory");
    }
}

// Pure writes with the EXACT store addressing of the real interior copy:
// 65 float4 per 1040-byte row, row starts at 16 mod 64.
__global__ __launch_bounds__(512) void probe_wpat(float* out, int reps)
{
    const int tid = threadIdx.x;
    for (int rep = 0; rep < reps; ++rep) {
        int bc = (blockIdx.x + rep * 331) & 1023;
        float* os = out + (size_t)bc * 67600;
        f32x4 val = {(float)rep, 1.f, 2.f, 3.f};
        for (int idx = tid; idx < 256 * 65; idx += 512) {
            int r = idx / 65, k = idx - r * 65;
            *(f32x4*)(os + (size_t)(r + 2) * 260 + 4 * k) = val;
        }
        asm volatile("" ::: "memory");
    }
}

// Pure aligned float4 reads of x.
__global__ __launch_bounds__(512) void probe_rlin(const float* __restrict__ x,
                                                  float* out, int reps)
{
    const int tid = threadIdx.x;
    float acc = 0.f;
    for (int rep = 0; rep < reps; ++rep) {
        int bc = (blockIdx.x + rep * 331) & 1023;
        const f32x4* xs = (const f32x4*)(x + (size_t)bc * 65536);
        for (int idx = tid; idx < 16384; idx += 512) {
            f32x4 v = xs[idx];
            acc += v.x + v.y + v.z + v.w;
        }
        asm volatile("" ::: "memory");
    }
    for (int o = 32; o > 0; o >>= 1) acc += __shfl_down(acc, o);
    if ((tid & 63) == 0)   // sink into out; fused kernel overwrites later
        out[(size_t)blockIdx.x * 8 + (tid >> 6)] = acc;
}

// Pure reads with the EXACT float2-pair load pattern of the real copy.
__global__ __launch_bounds__(512) void probe_rpat(const float* __restrict__ x,
                                                  float* out, int reps)
{
    const int tid = threadIdx.x;
    float acc = 0.f;
    for (int rep = 0; rep < reps; ++rep) {
        int bc = (blockIdx.x + rep * 331) & 1023;
        const float* xs = x + (size_t)bc * 65536;
        for (int idx = tid; idx < 256 * 65; idx += 512) {
            int r = idx / 65, k = idx - r * 65;
            const float* xrow = xs + (size_t)r * 256;
            if (k >= 1 && k < 64) {
                f32x2 a = *(const f32x2*)(xrow + 4 * k - 2);
                f32x2 c = *(const f32x2*)(xrow + 4 * k);
                acc += a.x + a.y + c.x + c.y;
            } else {
                f32x2 e = *(const f32x2*)(xrow + (k == 0 ? 0 : 254));
                acc += e.x + e.y;
            }
        }
        asm volatile("" ::: "memory");
    }
    for (int o = 32; o > 0; o >>= 1) acc += __shfl_down(acc, o);
    if ((tid & 63) == 0)
        out[4096 + (size_t)blockIdx.x * 8 + (tid >> 6)] = acc;
}

// ---------------- real (final, correct) kernel: R3 fused, phase D x dreps ----

template <int S>
__device__ __forceinline__ float mlp6(const float* v,
                                      const float* __restrict__ w1, const float* __restrict__ b1,
                                      const float* __restrict__ w2, const float* __restrict__ b2,
                                      const float* __restrict__ w3, const float* __restrict__ b3)
{
    const float* __restrict__ W1 = w1 + S * 48;
    const float* __restrict__ B1 = b1 + S * 8;
    const float* __restrict__ W2 = w2 + S * 64;
    const float* __restrict__ B2 = b2 + S * 8;
    const float* __restrict__ W3 = w3 + S * 8;
    const float  b3s = b3[S];
    float h1[8];
#pragma unroll
    for (int h = 0; h < 8; ++h) {
        float a = B1[h];
#pragma unroll
        for (int q = 0; q < 6; ++q) a = fmaf(v[q], W1[h * 6 + q], a);
        h1[h] = fmaxf(a, 0.f);
    }
    float h2[8];
#pragma unroll
    for (int g = 0; g < 8; ++g) {
        float a = B2[g];
#pragma unroll
        for (int h = 0; h < 8; ++h) a = fmaf(h1[h], W2[g * 8 + h], a);
        h2[g] = fmaxf(a, 0.f);
    }
    float o = b3s;
#pragma unroll
    for (int g = 0; g < 8; ++g) o = fmaf(h2[g], W3[g], o);
    return fmaxf(o, 0.f);
}

template <int S>
__device__ __forceinline__ void hstage(int it, int tid,
                                       float (*rowS)[260], float (*colS)[260],
                                       const float* __restrict__ w1, const float* __restrict__ b1,
                                       const float* __restrict__ w2, const float* __restrict__ b2,
                                       const float* __restrict__ w3, const float* __restrict__ b3)
{
    int rin0, rin1, rout;
    if (S == 0) { rin0 = 2 - it;   rin1 = 3 - it;   rout = 1 - it;   }
    else        { rin0 = 255 + it; rin1 = 256 + it; rout = 258 + it; }
    const int a0 = bmap(rin0), a1 = bmap(rin1), ao = bmap(rout);
    for (int j0 = tid; j0 < 258; j0 += 512) {
        int j = j0 + 1;
        float v[6];
        v[0] = rowS[a0][j - 1]; v[1] = rowS[a0][j]; v[2] = rowS[a0][j + 1];
        v[3] = rowS[a1][j - 1]; v[4] = rowS[a1][j]; v[5] = rowS[a1][j + 1];
        float o = mlp6<S>(v, w1, b1, w2, b2, w3, b3);
        rowS[ao][j] = o;
        if (j < 4 || j >= 255) colS[bmap(j)][rout] = o;
    }
}

template <int S>
__device__ __forceinline__ void vstage(int it, int tid,
                                       float (*rowS)[260], float (*colS)[260],
                                       const float* __restrict__ w1, const float* __restrict__ b1,
                                       const float* __restrict__ w2, const float* __restrict__ b2,
                                       const float* __restrict__ w3, const float* __restrict__ b3)
{
    int cin0, cin1, cout;
    if (S == 2) { cin0 = 2 - it;   cin1 = 3 - it;   cout = 1 - it;   }
    else        { cin0 = 255 + it; cin1 = 256 + it; cout = 258 + it; }
    const int a0 = bmap(cin0), a1 = bmap(cin1), ao = bmap(cout);
    for (int r0 = tid; r0 < 258; r0 += 512) {
        int r = r0 + 1;
        float v[6];
        v[0] = colS[a0][r - 1]; v[1] = colS[a0][r]; v[2] = colS[a0][r + 1];
        v[3] = colS[a1][r - 1]; v[4] = colS[a1][r]; v[5] = colS[a1][r + 1];
        float o = mlp6<S>(v, w1, b1, w2, b2, w3, b3);
        colS[ao][r] = o;
        if (r < 4 || r >= 255) rowS[bmap(r)][cout] = o;
    }
}

__global__ __launch_bounds__(512, 8) void fused_kernel(
    const float* __restrict__ x,
    const float* __restrict__ w1, const float* __restrict__ b1,
    const float* __restrict__ w2, const float* __restrict__ b2,
    const float* __restrict__ w3, const float* __restrict__ b3,
    float* __restrict__ out, int dreps)
{
    const int tid = threadIdx.x;
    const int bc  = blockIdx.x;
    const float* xs = x + (size_t)bc * 65536;
    float*       os = out + (size_t)bc * 67600;

    __shared__ float rowS[9][260];
    __shared__ float colS[9][260];

    for (int idx = tid; idx < 9 * 260; idx += 512) {
        (&rowS[0][0])[idx] = 0.f;
        (&colS[0][0])[idx] = 0.f;
    }
    __syncthreads();

    for (int idx = tid; idx < 5 * 256; idx += 512) {
        int which = idx >> 8, t = idx & 255;
        int xr = which < 2 ? which : 251 + which;
        rowS[2 + which][2 + t] = xs[xr * 256 + t];
    }
    for (int idx = tid; idx < 5 * 256; idx += 512) {
        int which = idx >> 8, t = idx & 255;
        int xr = which < 2 ? which : 251 + which;
        colS[2 + which][2 + t] = xs[t * 256 + xr];
    }
    __syncthreads();

    for (int it = 0; it < 2; ++it) {
        hstage<0>(it, tid, rowS, colS, w1, b1, w2, b2, w3, b3);
        hstage<1>(it, tid, rowS, colS, w1, b1, w2, b2, w3, b3);
        __syncthreads();
        vstage<2>(it, tid, rowS, colS, w1, b1, w2, b2, w3, b3);
        vstage<3>(it, tid, rowS, colS, w1, b1, w2, b2, w3, b3);
        __syncthreads();
    }

    // frame rows 0,1,258,259
    for (int idx = tid; idx < 4 * 260; idx += 512) {
        int w = idx / 260, cc = idx % 260;
        int rr = w < 2 ? w : 256 + w;
        os[(size_t)rr * 260 + cc] = rowS[bmap(rr)][cc];
    }

    // interior rows, repeated dreps times (diagnostic visibility)
    for (int rep = 0; rep < dreps; ++rep) {
        for (int idx = tid; idx < 256 * 65; idx += 512) {
            int r = idx / 65;
            int k = idx - r * 65;
            int rp = r + 2;
            float* orow = os + (size_t)rp * 260;
            const float* xrow = xs + (size_t)r * 256;
            f32x4 val;
            if (k == 0) {
                val = (f32x4){colS[0][rp], colS[1][rp], colS[2][rp], colS[3][rp]};
            } else if (k == 64) {
                val = (f32x4){colS[5][rp], colS[6][rp], colS[7][rp], colS[8][rp]};
            } else {
                f32x2 a = *(const f32x2*)(xrow + 4 * k - 2);
                f32x2 c = *(const f32x2*)(xrow + 4 * k);
                val = (f32x4){a.x, a.y, c.x, c.y};
            }
            *(f32x4*)(orow + 4 * k) = val;
        }
        asm volatile("" ::: "memory");
    }
}

extern "C" void kernel_launch(void* const* d_in, const int* in_sizes, int n_in,
                              void* d_out, int out_size, void* d_ws, size_t ws_size,
                              hipStream_t stream)
{
    const float* x  = (const float*)d_in[0];
    const float* w1 = (const float*)d_in[1];
    const float* b1 = (const float*)d_in[2];
    const float* w2 = (const float*)d_in[3];
    const float* b2 = (const float*)d_in[4];
    const float* w3 = (const float*)d_in[5];
    const float* b3 = (const float*)d_in[6];
    float* out = (float*)d_out;

    // probes (may write garbage; fused rewrites everything afterwards)
    probe_wlin<<<1024, 512, 0, stream>>>(out, 5);
    probe_wpat<<<1024, 512, 0, stream>>>(out, 5);
    probe_rlin<<<1024, 512, 0, stream>>>(x, out, 5);
    probe_rpat<<<1024, 512, 0, stream>>>(x, out, 5);

    // final correct writer (phase D doubled for counter visibility)
    fused_kernel<<<1024, 512, 0, stream>>>(x, w1, b1, w2, b2, w3, b3, out, 2);
}

// Round 5
// 234.222 us; speedup vs baseline: 4.3186x; 4.3186x over previous
//
#include <hip/hip_runtime.h>

// B=8, C=128, H=W=256, P=2, R=2, WP=3, HID=8. Output xp: (B,C,260,260) fp32.
// Single kernel, grid 2048 x 512:
//   even blocks (bid&1==0): pure streaming copy of slice bid/2 interior,
//       xp cols 2..257 only (float2 + 63*float4 + float2 per row). No
//       dependence on border results, no barriers.
//   odd blocks: border program for slice bid/2 in LDS (4-stage schedule,
//       SGPR weights), then writes frame rows 0,1,258,259 (full width) and
//       col strips (cols 0,1 and 258,259, rows 2..257).
// Interleaving hides the border blocks' latency inside the BW-bound copy.

typedef float f32x4 __attribute__((ext_vector_type(4)));
typedef float f32x2 __attribute__((ext_vector_type(2)));

__device__ __forceinline__ int bmap(int r) { return r < 4 ? r : r - 251; }

template <int S>
__device__ __forceinline__ float mlp6(const float* v,
                                      const float* __restrict__ w1, const float* __restrict__ b1,
                                      const float* __restrict__ w2, const float* __restrict__ b2,
                                      const float* __restrict__ w3, const float* __restrict__ b3)
{
    const float* __restrict__ W1 = w1 + S * 48;  // [8][6]
    const float* __restrict__ B1 = b1 + S * 8;
    const float* __restrict__ W2 = w2 + S * 64;  // [8][8]
    const float* __restrict__ B2 = b2 + S * 8;
    const float* __restrict__ W3 = w3 + S * 8;
    const float  b3s = b3[S];

    float h1[8];
#pragma unroll
    for (int h = 0; h < 8; ++h) {
        float a = B1[h];
#pragma unroll
        for (int q = 0; q < 6; ++q) a = fmaf(v[q], W1[h * 6 + q], a);
        h1[h] = fmaxf(a, 0.f);
    }
    float h2[8];
#pragma unroll
    for (int g = 0; g < 8; ++g) {
        float a = B2[g];
#pragma unroll
        for (int h = 0; h < 8; ++h) a = fmaf(h1[h], W2[g * 8 + h], a);
        h2[g] = fmaxf(a, 0.f);
    }
    float o = b3s;
#pragma unroll
    for (int g = 0; g < 8; ++g) o = fmaf(h2[g], W3[g], o);
    return fmaxf(o, 0.f);
}

template <int S>
__device__ __forceinline__ void hstage(int it, int tid,
                                       float (*rowS)[260], float (*colS)[260],
                                       const float* __restrict__ w1, const float* __restrict__ b1,
                                       const float* __restrict__ w2, const float* __restrict__ b2,
                                       const float* __restrict__ w3, const float* __restrict__ b3)
{
    int rin0, rin1, rout;
    if (S == 0) { rin0 = 2 - it;   rin1 = 3 - it;   rout = 1 - it;   }
    else        { rin0 = 255 + it; rin1 = 256 + it; rout = 258 + it; }
    const int a0 = bmap(rin0), a1 = bmap(rin1), ao = bmap(rout);
    for (int j0 = tid; j0 < 258; j0 += 512) {
        int j = j0 + 1;
        float v[6];
        v[0] = rowS[a0][j - 1]; v[1] = rowS[a0][j]; v[2] = rowS[a0][j + 1];
        v[3] = rowS[a1][j - 1]; v[4] = rowS[a1][j]; v[5] = rowS[a1][j + 1];
        float o = mlp6<S>(v, w1, b1, w2, b2, w3, b3);
        rowS[ao][j] = o;
        if (j < 4 || j >= 255) colS[bmap(j)][rout] = o;  // keep col views consistent
    }
}

template <int S>
__device__ __forceinline__ void vstage(int it, int tid,
                                       float (*rowS)[260], float (*colS)[260],
                                       const float* __restrict__ w1, const float* __restrict__ b1,
                                       const float* __restrict__ w2, const float* __restrict__ b2,
                                       const float* __restrict__ w3, const float* __restrict__ b3)
{
    int cin0, cin1, cout;
    if (S == 2) { cin0 = 2 - it;   cin1 = 3 - it;   cout = 1 - it;   }
    else        { cin0 = 255 + it; cin1 = 256 + it; cout = 258 + it; }
    const int a0 = bmap(cin0), a1 = bmap(cin1), ao = bmap(cout);
    for (int r0 = tid; r0 < 258; r0 += 512) {
        int r = r0 + 1;
        float v[6];
        v[0] = colS[a0][r - 1]; v[1] = colS[a0][r]; v[2] = colS[a0][r + 1];
        v[3] = colS[a1][r - 1]; v[4] = colS[a1][r]; v[5] = colS[a1][r + 1];
        float o = mlp6<S>(v, w1, b1, w2, b2, w3, b3);
        colS[ao][r] = o;
        if (r < 4 || r >= 255) rowS[bmap(r)][cout] = o;  // keep row views consistent
    }
}

__global__ __launch_bounds__(512) void padding_kernel(
    const float* __restrict__ x,
    const float* __restrict__ w1, const float* __restrict__ b1,
    const float* __restrict__ w2, const float* __restrict__ b2,
    const float* __restrict__ w3, const float* __restrict__ b3,
    float* __restrict__ out)
{
    const int tid = threadIdx.x;
    const int bc  = blockIdx.x >> 1;
    const bool is_border = (blockIdx.x & 1) != 0;
    const float* xs = x + (size_t)bc * 65536;
    float*       os = out + (size_t)bc * 67600;

    __shared__ float rowS[9][260];
    __shared__ float colS[9][260];

    if (!is_border) {
        // ---------- pure streaming copy: xp[rp][2..257] = x[r][0..255] ----------
        for (int idx = tid; idx < 256 * 65; idx += 512) {
            int r = idx / 65;
            int k = idx - r * 65;
            float*       orow = os + (size_t)(r + 2) * 260;
            const float* xrow = xs + (size_t)r * 256;
            if (k == 0) {
                *(f32x2*)(orow + 2)   = *(const f32x2*)(xrow);         // cols 2,3
            } else if (k == 64) {
                *(f32x2*)(orow + 256) = *(const f32x2*)(xrow + 254);   // cols 256,257
            } else {
                f32x2 a = *(const f32x2*)(xrow + 4 * k - 2);
                f32x2 c = *(const f32x2*)(xrow + 4 * k);
                *(f32x4*)(orow + 4 * k) = (f32x4){a.x, a.y, c.x, c.y}; // cols 4k..4k+3
            }
        }
        return;
    }

    // ---------- border program ----------
    for (int idx = tid; idx < 9 * 260; idx += 512) {
        (&rowS[0][0])[idx] = 0.f;
        (&colS[0][0])[idx] = 0.f;
    }
    __syncthreads();

    // xp rows 2,3 = x rows 0,1 ; xp rows 255,256,257 = x rows 253,254,255 (cols likewise)
    for (int idx = tid; idx < 5 * 256; idx += 512) {
        int which = idx >> 8, t = idx & 255;
        int xr = which < 2 ? which : 251 + which;   // 0,1,253,254,255
        rowS[2 + which][2 + t] = xs[xr * 256 + t];
    }
    for (int idx = tid; idx < 5 * 256; idx += 512) {
        int which = idx >> 8, t = idx & 255;
        int xr = which < 2 ? which : 251 + which;
        colS[2 + which][2 + t] = xs[t * 256 + xr];
    }
    __syncthreads();

    for (int it = 0; it < 2; ++it) {
        hstage<0>(it, tid, rowS, colS, w1, b1, w2, b2, w3, b3);
        hstage<1>(it, tid, rowS, colS, w1, b1, w2, b2, w3, b3);
        __syncthreads();
        vstage<2>(it, tid, rowS, colS, w1, b1, w2, b2, w3, b3);
        vstage<3>(it, tid, rowS, colS, w1, b1, w2, b2, w3, b3);
        __syncthreads();
    }

    // frame rows 0,1,258,259 full width (corners are LDS zeros, matching ref)
    for (int idx = tid; idx < 4 * 260; idx += 512) {
        int w = idx / 260, cc = idx % 260;
        int rr = w < 2 ? w : 256 + w;               // 0,1,258,259
        os[(size_t)rr * 260 + cc] = rowS[bmap(rr)][cc];
    }
    // col strips: cols 0,1 and 258,259 for rows 2..257
    for (int idx = tid; idx < 2 * 256; idx += 512) {
        int w = idx >> 8;                           // 0 = left, 1 = right
        int r = (idx & 255) + 2;
        float* orow = os + (size_t)r * 260;
        if (w == 0) *(f32x2*)(orow)       = (f32x2){colS[0][r], colS[1][r]};
        else        *(f32x2*)(orow + 258) = (f32x2){colS[7][r], colS[8][r]};
    }
}

extern "C" void kernel_launch(void* const* d_in, const int* in_sizes, int n_in,
                              void* d_out, int out_size, void* d_ws, size_t ws_size,
                              hipStream_t stream)
{
    const float* x  = (const float*)d_in[0];
    const float* w1 = (const float*)d_in[1];
    const float* b1 = (const float*)d_in[2];
    const float* w2 = (const float*)d_in[3];
    const float* b2 = (const float*)d_in[4];
    const float* w3 = (const float*)d_in[5];
    const float* b3 = (const float*)d_in[6];
    float* out = (float*)d_out;

    padding_kernel<<<2048, 512, 0, stream>>>(x, w1, b1, w2, b2, w3, b3, out);
}

// Round 6
// 152.017 us; speedup vs baseline: 6.6540x; 1.5408x over previous
//
#include <hip/hip_runtime.h>

// B=8, C=128, H=W=256, P=2, R=2, WP=3, HID=8. Output xp: (B,C,260,260) fp32.
// One block per (b,c) slice, 512 threads:
//   0) zero-init LDS row/col line buffers -> sync
//   1) coalesced load of 5 tracked x rows into rowS; r-major interior stream
//      xp[r+2][2..257] = x[r][0..255] (f32x2+f32x4, coalesced), HARVESTING the
//      border column data (x cols 0,1,253,254,255) into colS via LDS stores.
//      -> NO strided global column gather anywhere.
//   2) sync; 4-stage border program {top,bot}->{left,right} x2 in LDS,
//      weights via wave-uniform scalar (SGPR) loads; pure LDS+VALU.
//   3) write frame rows 0,1,258,259 and col strips (cols 0,1 / 258,259).

typedef float f32x4 __attribute__((ext_vector_type(4)));
typedef float f32x2 __attribute__((ext_vector_type(2)));

__device__ __forceinline__ int bmap(int r) { return r < 4 ? r : r - 251; }

template <int S>
__device__ __forceinline__ float mlp6(const float* v,
                                      const float* __restrict__ w1, const float* __restrict__ b1,
                                      const float* __restrict__ w2, const float* __restrict__ b2,
                                      const float* __restrict__ w3, const float* __restrict__ b3)
{
    const float* __restrict__ W1 = w1 + S * 48;  // [8][6]
    const float* __restrict__ B1 = b1 + S * 8;
    const float* __restrict__ W2 = w2 + S * 64;  // [8][8]
    const float* __restrict__ B2 = b2 + S * 8;
    const float* __restrict__ W3 = w3 + S * 8;
    const float  b3s = b3[S];

    float h1[8];
#pragma unroll
    for (int h = 0; h < 8; ++h) {
        float a = B1[h];
#pragma unroll
        for (int q = 0; q < 6; ++q) a = fmaf(v[q], W1[h * 6 + q], a);
        h1[h] = fmaxf(a, 0.f);
    }
    float h2[8];
#pragma unroll
    for (int g = 0; g < 8; ++g) {
        float a = B2[g];
#pragma unroll
        for (int h = 0; h < 8; ++h) a = fmaf(h1[h], W2[g * 8 + h], a);
        h2[g] = fmaxf(a, 0.f);
    }
    float o = b3s;
#pragma unroll
    for (int g = 0; g < 8; ++g) o = fmaf(h2[g], W3[g], o);
    return fmaxf(o, 0.f);
}

template <int S>
__device__ __forceinline__ void hstage(int it, int tid,
                                       float (*rowS)[260], float (*colS)[260],
                                       const float* __restrict__ w1, const float* __restrict__ b1,
                                       const float* __restrict__ w2, const float* __restrict__ b2,
                                       const float* __restrict__ w3, const float* __restrict__ b3)
{
    int rin0, rin1, rout;
    if (S == 0) { rin0 = 2 - it;   rin1 = 3 - it;   rout = 1 - it;   }
    else        { rin0 = 255 + it; rin1 = 256 + it; rout = 258 + it; }
    const int a0 = bmap(rin0), a1 = bmap(rin1), ao = bmap(rout);
    for (int j0 = tid; j0 < 258; j0 += 512) {
        int j = j0 + 1;
        float v[6];
        v[0] = rowS[a0][j - 1]; v[1] = rowS[a0][j]; v[2] = rowS[a0][j + 1];
        v[3] = rowS[a1][j - 1]; v[4] = rowS[a1][j]; v[5] = rowS[a1][j + 1];
        float o = mlp6<S>(v, w1, b1, w2, b2, w3, b3);
        rowS[ao][j] = o;
        if (j < 4 || j >= 255) colS[bmap(j)][rout] = o;  // keep col views consistent
    }
}

template <int S>
__device__ __forceinline__ void vstage(int it, int tid,
                                       float (*rowS)[260], float (*colS)[260],
                                       const float* __restrict__ w1, const float* __restrict__ b1,
                                       const float* __restrict__ w2, const float* __restrict__ b2,
                                       const float* __restrict__ w3, const float* __restrict__ b3)
{
    int cin0, cin1, cout;
    if (S == 2) { cin0 = 2 - it;   cin1 = 3 - it;   cout = 1 - it;   }
    else        { cin0 = 255 + it; cin1 = 256 + it; cout = 258 + it; }
    const int a0 = bmap(cin0), a1 = bmap(cin1), ao = bmap(cout);
    for (int r0 = tid; r0 < 258; r0 += 512) {
        int r = r0 + 1;
        float v[6];
        v[0] = colS[a0][r - 1]; v[1] = colS[a0][r]; v[2] = colS[a0][r + 1];
        v[3] = colS[a1][r - 1]; v[4] = colS[a1][r]; v[5] = colS[a1][r + 1];
        float o = mlp6<S>(v, w1, b1, w2, b2, w3, b3);
        colS[ao][r] = o;
        if (r < 4 || r >= 255) rowS[bmap(r)][cout] = o;  // keep row views consistent
    }
}

__global__ __launch_bounds__(512, 8) void padding_kernel(
    const float* __restrict__ x,
    const float* __restrict__ w1, const float* __restrict__ b1,
    const float* __restrict__ w2, const float* __restrict__ b2,
    const float* __restrict__ w3, const float* __restrict__ b3,
    float* __restrict__ out)
{
    const int tid = threadIdx.x;
    const int bc  = blockIdx.x;                     // b*128 + c
    const float* xs = x + (size_t)bc * 65536;
    float*       os = out + (size_t)bc * 67600;

    // tracked xp rows/cols {0,1,2,3,255,256,257,258,259} -> index 0..8
    __shared__ float rowS[9][260];
    __shared__ float colS[9][260];

    // 0) zero-init
    for (int idx = tid; idx < 9 * 260; idx += 512) {
        (&rowS[0][0])[idx] = 0.f;
        (&colS[0][0])[idx] = 0.f;
    }
    __syncthreads();

    // 1a) coalesced load of 5 tracked rows: xp rows 2,3,255,256,257
    for (int idx = tid; idx < 5 * 256; idx += 512) {
        int which = idx >> 8, t = idx & 255;
        int xr = which < 2 ? which : 251 + which;   // x rows 0,1,253,254,255
        rowS[2 + which][2 + t] = xs[xr * 256 + t];
    }

    // 1b) interior stream + column harvest (r-major, coalesced)
    //   k==0 : xp cols 2,3   <- x cols 0,1     ; harvest colS[2],colS[3]
    //   k==63: xp cols 252..255 <- x 250..253  ; harvest colS[4] (x col 253)
    //   k==64: xp cols 256,257 <- x cols 254,255; harvest colS[5],colS[6]
    for (int idx = tid; idx < 256 * 65; idx += 512) {
        int r  = idx / 65;
        int k  = idx - r * 65;
        int rp = r + 2;
        float*       orow = os + (size_t)rp * 260;
        const float* xrow = xs + (size_t)r * 256;
        if (k == 0) {
            f32x2 a = *(const f32x2*)(xrow);
            *(f32x2*)(orow + 2) = a;
            colS[2][rp] = a.x;                      // xp col 2 = x col 0
            colS[3][rp] = a.y;                      // xp col 3 = x col 1
        } else if (k == 63) {
            f32x2 a = *(const f32x2*)(xrow + 250);
            f32x2 c = *(const f32x2*)(xrow + 252);
            *(f32x4*)(orow + 252) = (f32x4){a.x, a.y, c.x, c.y};
            colS[4][rp] = c.y;                      // xp col 255 = x col 253
        } else if (k == 64) {
            f32x2 c = *(const f32x2*)(xrow + 254);
            *(f32x2*)(orow + 256) = c;
            colS[5][rp] = c.x;                      // xp col 256 = x col 254
            colS[6][rp] = c.y;                      // xp col 257 = x col 255
        } else {
            f32x2 a = *(const f32x2*)(xrow + 4 * k - 2);
            f32x2 c = *(const f32x2*)(xrow + 4 * k);
            *(f32x4*)(orow + 4 * k) = (f32x4){a.x, a.y, c.x, c.y};
        }
    }
    __syncthreads();

    // 2) border program — pure LDS+VALU
    for (int it = 0; it < 2; ++it) {
        hstage<0>(it, tid, rowS, colS, w1, b1, w2, b2, w3, b3);
        hstage<1>(it, tid, rowS, colS, w1, b1, w2, b2, w3, b3);
        __syncthreads();
        vstage<2>(it, tid, rowS, colS, w1, b1, w2, b2, w3, b3);
        vstage<3>(it, tid, rowS, colS, w1, b1, w2, b2, w3, b3);
        __syncthreads();
    }

    // 3) frame rows 0,1,258,259 (full width; corners stay 0 as in ref)
    for (int idx = tid; idx < 4 * 260; idx += 512) {
        int w = idx / 260, cc = idx % 260;
        int rr = w < 2 ? w : 256 + w;               // 0,1,258,259
        os[(size_t)rr * 260 + cc] = rowS[bmap(rr)][cc];
    }
    // col strips: cols 0,1 and 258,259 for rows 2..257
    for (int idx = tid; idx < 2 * 256; idx += 512) {
        int w = idx >> 8;                           // 0 = left, 1 = right
        int r = (idx & 255) + 2;
        float* orow = os + (size_t)r * 260;
        if (w == 0) *(f32x2*)(orow)       = (f32x2){colS[0][r], colS[1][r]};
        else        *(f32x2*)(orow + 258) = (f32x2){colS[7][r], colS[8][r]};
    }
}

extern "C" void kernel_launch(void* const* d_in, const int* in_sizes, int n_in,
                              void* d_out, int out_size, void* d_ws, size_t ws_size,
                              hipStream_t stream)
{
    const float* x  = (const float*)d_in[0];
    const float* w1 = (const float*)d_in[1];
    const float* b1 = (const float*)d_in[2];
    const float* w2 = (const float*)d_in[3];
    const float* b2 = (const float*)d_in[4];
    const float* w3 = (const float*)d_in[5];
    const float* b3 = (const float*)d_in[6];
    float* out = (float*)d_out;

    padding_kernel<<<1024, 512, 0, stream>>>(x, w1, b1, w2, b2, w3, b3, out);
}